// Round 1
// baseline (770.170 us; speedup 1.0000x reference)
//
#include <hip/hip_runtime.h>
#include <math.h>

#define KCODES 2048
#define DIM 64
#define NROWS 65536          // 64*32*32
#define NELEM (NROWS * DIM)  // 4194304

// ws layout (bytes):
//   0      .. 8191   : hist[2048] (int)
//   8192   .. 16383  : c2[2048]  (float)  sum of squares per codebook column
//   16384  .. 16387  : sse (float)        sum of squared (q - x)
#define WS_HIST 0
#define WS_C2   8192
#define WS_SSE  16384

// c2[k] = sum_d cb[d][k]^2   (codebook layout is [D][K], k-coalesced)
__global__ void vq_colnorm(const float* __restrict__ cb, float* __restrict__ c2) {
  int k = blockIdx.x * 256 + threadIdx.x;
  float s = 0.f;
#pragma unroll
  for (int d = 0; d < DIM; ++d) {
    float v = cb[d * KCODES + k];
    s = fmaf(v, v, s);
  }
  c2[k] = s;
}

// Block = 256 threads = 4 waves. Each block handles 64 rows.
// Wave w scans codes [w*512, w*512+512) for all 64 rows (1 row/lane).
// Partial argmins combined in LDS (ascending-k order, strict < => first-min
// tie-break identical to jnp.argmin). Then fused epilogue: histogram,
// codebook gather, STE write, SSE reduction.
__global__ __launch_bounds__(256, 4) void vq_main(
    const float* __restrict__ inp, const float* __restrict__ cb,
    const float* __restrict__ c2, int* __restrict__ hist,
    float* __restrict__ sse, float* __restrict__ out)
{
  __shared__ float s_bd[4][64];
  __shared__ int   s_bk[4][64];
  __shared__ int   s_k[64];
  __shared__ float s_red[4];

  const int t = threadIdx.x;
  const int lane = t & 63;
  // readfirstlane => compiler-provable wave-uniform k-range => s_load codebook
  const int wave = __builtin_amdgcn_readfirstlane(t >> 6);
  const int rowblk = blockIdx.x * 64;
  const int row = rowblk + lane;

  // x row into registers (16 x float4 = 64 VGPRs)
  float4 x4[16];
  const float4* xp = (const float4*)(inp + row * DIM);
#pragma unroll
  for (int i = 0; i < 16; ++i) x4[i] = xp[i];

  float x2 = 0.f;
#pragma unroll
  for (int i = 0; i < 16; ++i) {
    x2 = fmaf(x4[i].x, x4[i].x, x2);
    x2 = fmaf(x4[i].y, x4[i].y, x2);
    x2 = fmaf(x4[i].z, x4[i].z, x2);
    x2 = fmaf(x4[i].w, x4[i].w, x2);
  }

  const int kbeg = wave * (KCODES / 4);
  float bestd = INFINITY;
  int bestk = 0;

  for (int k0 = kbeg; k0 < kbeg + (KCODES / 4); k0 += 8) {
    float a[8];
#pragma unroll
    for (int j = 0; j < 8; ++j) a[j] = 0.f;
#pragma unroll
    for (int dv = 0; dv < 16; ++dv) {
      const float xs0 = x4[dv].x, xs1 = x4[dv].y, xs2 = x4[dv].z, xs3 = x4[dv].w;
      const float* r0 = cb + (dv * 4 + 0) * KCODES + k0;
      const float* r1 = cb + (dv * 4 + 1) * KCODES + k0;
      const float* r2 = cb + (dv * 4 + 2) * KCODES + k0;
      const float* r3 = cb + (dv * 4 + 3) * KCODES + k0;
#pragma unroll
      for (int j = 0; j < 8; ++j) a[j] = fmaf(xs0, r0[j], a[j]);
#pragma unroll
      for (int j = 0; j < 8; ++j) a[j] = fmaf(xs1, r1[j], a[j]);
#pragma unroll
      for (int j = 0; j < 8; ++j) a[j] = fmaf(xs2, r2[j], a[j]);
#pragma unroll
      for (int j = 0; j < 8; ++j) a[j] = fmaf(xs3, r3[j], a[j]);
    }
#pragma unroll
    for (int j = 0; j < 8; ++j) {
      // mirror reference rounding: (x2 - 2*dot) + c2
      float dist = (x2 - 2.0f * a[j]) + c2[k0 + j];
      if (dist < bestd) { bestd = dist; bestk = k0 + j; }
    }
  }

  s_bd[wave][lane] = bestd;
  s_bk[wave][lane] = bestk;
  __syncthreads();

  if (t < 64) {
    float bd = s_bd[0][t];
    int bk = s_bk[0][t];
#pragma unroll
    for (int s = 1; s < 4; ++s) {
      float d2 = s_bd[s][t];
      int k2 = s_bk[s][t];
      if (d2 < bd) { bd = d2; bk = k2; }  // strict < keeps lowest-k on tie
    }
    s_k[t] = bk;
    atomicAdd(&hist[bk], 1);
  }
  __syncthreads();

  // Epilogue over all 256 threads: thread t -> row (t>>2), dims [(t&3)*16, +16)
  const int fr = t >> 2;
  const int fd = (t & 3) * 16;
  const int grow = rowblk + fr;
  const int myk = s_k[fr];
  const float* xrow = inp + grow * DIM + fd;
  float* orow = out + grow * DIM + fd;
  float serr = 0.f;
#pragma unroll
  for (int i = 0; i < 16; ++i) {
    float xv = xrow[i];
    float qv = cb[(fd + i) * KCODES + myk];
    float dq = qv - xv;
    serr = fmaf(dq, dq, serr);
    orow[i] = xv + dq;  // ste = x + (q - x)
  }

#pragma unroll
  for (int off = 32; off > 0; off >>= 1) serr += __shfl_down(serr, off, 64);
  if (lane == 0) s_red[wave] = serr;
  __syncthreads();
  if (t == 0) atomicAdd(sse, s_red[0] + s_red[1] + s_red[2] + s_red[3]);
}

__global__ void vq_final(const int* __restrict__ hist,
                         const float* __restrict__ sse,
                         float* __restrict__ out) {
  __shared__ float s_red[4];
  const int t = threadIdx.x;
  float s = 0.f;
  for (int k = t; k < KCODES; k += 256) {
    float p = (float)hist[k] * (1.0f / NROWS);
    s += p * logf(p + 1e-10f);
  }
#pragma unroll
  for (int off = 32; off > 0; off >>= 1) s += __shfl_down(s, off, 64);
  if ((t & 63) == 0) s_red[t >> 6] = s;
  __syncthreads();
  if (t == 0) {
    float tot = s_red[0] + s_red[1] + s_red[2] + s_red[3];
    out[NELEM] = expf(-tot);                 // perplexity
    float cl = *sse * (1.0f / NELEM);
    out[NELEM + 1] = cl;                     // codebook_loss
    out[NELEM + 2] = 0.25f * cl;             // commitment_loss
  }
}

extern "C" void kernel_launch(void* const* d_in, const int* in_sizes, int n_in,
                              void* d_out, int out_size, void* d_ws, size_t ws_size,
                              hipStream_t stream) {
  const float* inp = (const float*)d_in[0];
  const float* cb  = (const float*)d_in[1];
  float* out = (float*)d_out;
  char* ws = (char*)d_ws;
  int* hist  = (int*)(ws + WS_HIST);
  float* c2  = (float*)(ws + WS_C2);
  float* sse = (float*)(ws + WS_SSE);

  hipMemsetAsync(d_ws, 0, WS_SSE + 16, stream);
  vq_colnorm<<<KCODES / 256, 256, 0, stream>>>(cb, c2);
  vq_main<<<NROWS / 64, 256, 0, stream>>>(inp, cb, c2, hist, sse, out);
  vq_final<<<1, 256, 0, stream>>>(hist, sse, out);
}

// Round 2
// 206.289 us; speedup vs baseline: 3.7335x; 3.7335x over previous
//
#include <hip/hip_runtime.h>
#include <math.h>

#define KCODES 2048
#define DIM 64
#define NROWS 65536          // 64*32*32
#define NELEM (NROWS * DIM)  // 4194304

// ws layout (bytes):
//   0      .. 8191   : hist[2048] (int)
//   8192   .. 16383  : c2[2048]  (float)
//   16384  .. 16387  : sse (float)
#define WS_HIST 0
#define WS_C2   8192
#define WS_SSE  16384

#define EPSM 2e-3f   // argmin margin below which we re-resolve in exact fp32

typedef float  floatx4 __attribute__((ext_vector_type(4)));
typedef short  short8  __attribute__((ext_vector_type(8)));

__device__ __forceinline__ unsigned short f2bf(float f) {
  union { float f; unsigned u; } a; a.f = f;
  unsigned r = (a.u + 0x7FFFu + ((a.u >> 16) & 1u)) >> 16;  // RNE, inputs finite
  return (unsigned short)r;
}
__device__ __forceinline__ float bf2f(unsigned short h) {
  union { unsigned u; float f; } a; a.u = ((unsigned)h) << 16;
  return a.f;
}

// c2[k] = sum_d cb[d][k]^2  (same arithmetic/order as round 1 — fixup relies on it)
__global__ void vq_colnorm(const float* __restrict__ cb, float* __restrict__ c2) {
  int k = blockIdx.x * 256 + threadIdx.x;
  float s = 0.f;
#pragma unroll
  for (int d = 0; d < DIM; ++d) {
    float v = cb[d * KCODES + k];
    s = fmaf(v, v, s);
  }
  c2[k] = s;
}

// Block = 256 thr = 4 waves; wave owns 32 rows (2 MFMA row-tiles), block = 128 rows.
// K-loop over 64 tiles of 32 codes, codebook hi/lo staged in LDS (double buffer,
// XOR-swizzled 16B blocks: pb = kb ^ (n&7) -> both ds_read_b128 and ds_write_b128
// at the 8-words/bank floor).
__global__ __launch_bounds__(256, 2) void vq_main(
    const float* __restrict__ inp, const float* __restrict__ cb,
    const float* __restrict__ c2, int* __restrict__ hist,
    float* __restrict__ sse, float* __restrict__ out)
{
  __shared__ __align__(16) short Bh[2][2][32][64]; // [buf][hi/lo][code n][dim k], swizzled
  __shared__ int   s_k[128];
  __shared__ int   s_nflag;
  __shared__ int   s_frows[128];
  __shared__ float s_rd[256];
  __shared__ int   s_rk[256];
  __shared__ float s_red[4];

  const int t    = threadIdx.x;
  const int lane = t & 63;
  const int wave = __builtin_amdgcn_readfirstlane(t >> 6);
  const int c    = lane & 15;   // MFMA m / n / col-of-D index
  const int q    = lane >> 4;   // MFMA quad
  const int c7   = c & 7;
  const int rowbase = blockIdx.x * 128 + wave * 32;

  if (t == 0) s_nflag = 0;

  // ---- A fragments (x rows) in registers: hi/lo bf16, [rowtile r][kstep s] ----
  short8 Ah[2][2], Al[2][2];
#pragma unroll
  for (int r = 0; r < 2; ++r) {
#pragma unroll
    for (int s = 0; s < 2; ++s) {
      const float* px = inp + (size_t)(rowbase + r * 16 + c) * 64 + s * 32 + q * 8;
      float4 u0 = *(const float4*)px;
      float4 u1 = *(const float4*)(px + 4);
      float u[8] = {u0.x, u0.y, u0.z, u0.w, u1.x, u1.y, u1.z, u1.w};
      short8 hh, ll;
#pragma unroll
      for (int e = 0; e < 8; ++e) {
        unsigned short hb = f2bf(u[e]);
        float lo = u[e] - bf2f(hb);
        hh[e] = (short)hb;
        ll[e] = (short)f2bf(lo);
      }
      Ah[r][s] = hh; Al[r][s] = ll;
    }
  }

  // per-lane argmin state for 8 rows (r*4+reg), codes restricted to col c (+16n)
  float d1[8], d2[8];
  int   k1[8];
#pragma unroll
  for (int i = 0; i < 8; ++i) { d1[i] = INFINITY; d2[i] = INFINITY; k1[i] = 0; }

  const int sn  = t & 31;   // staging: code within 32-tile
  const int sdg = t >> 5;   // staging: 8-dim group
  const int spb = sdg ^ (sn & 7);
  const float* cbp = cb + (size_t)sdg * 8 * KCODES + sn;

  // ---- prologue: stage tile 0 into buf 0 ----
  {
    float pv[8];
#pragma unroll
    for (int i = 0; i < 8; ++i) pv[i] = cbp[(size_t)i * KCODES];
    short8 hh, ll;
#pragma unroll
    for (int e = 0; e < 8; ++e) {
      unsigned short hb = f2bf(pv[e]);
      float lo = pv[e] - bf2f(hb);
      hh[e] = (short)hb; ll[e] = (short)f2bf(lo);
    }
    *(short8*)&Bh[0][0][sn][spb * 8] = hh;
    *(short8*)&Bh[0][1][sn][spb * 8] = ll;
  }
  __syncthreads();

  const floatx4 zero = {0.f, 0.f, 0.f, 0.f};

#pragma unroll 2
  for (int j = 0; j < 64; ++j) {
    const int buf = j & 1;
    const bool has_next = (j + 1) < 64;
    float pv[8];
    if (has_next) {
#pragma unroll
      for (int i = 0; i < 8; ++i) pv[i] = cbp[(size_t)i * KCODES + (j + 1) * 32];
    }
    float c2v0 = c2[j * 32 + c];
    float c2v1 = c2[j * 32 + 16 + c];

#pragma unroll
    for (int nt = 0; nt < 2; ++nt) {
      const int rowi = nt * 16 + c;
      short8 bh0 = *(const short8*)&Bh[buf][0][rowi][((0 + q) ^ c7) * 8];
      short8 bh1 = *(const short8*)&Bh[buf][0][rowi][((4 + q) ^ c7) * 8];
      short8 bl0 = *(const short8*)&Bh[buf][1][rowi][((0 + q) ^ c7) * 8];
      short8 bl1 = *(const short8*)&Bh[buf][1][rowi][((4 + q) ^ c7) * 8];
      const float c2v = nt ? c2v1 : c2v0;
      const int kc = j * 32 + nt * 16 + c;
#pragma unroll
      for (int r = 0; r < 2; ++r) {
        floatx4 am = __builtin_amdgcn_mfma_f32_16x16x32_bf16(Ah[r][0], bh0, zero, 0, 0, 0);
        am = __builtin_amdgcn_mfma_f32_16x16x32_bf16(Ah[r][1], bh1, am, 0, 0, 0);
        floatx4 ax = __builtin_amdgcn_mfma_f32_16x16x32_bf16(Ah[r][0], bl0, zero, 0, 0, 0);
        ax = __builtin_amdgcn_mfma_f32_16x16x32_bf16(Al[r][0], bh0, ax, 0, 0, 0);
        ax = __builtin_amdgcn_mfma_f32_16x16x32_bf16(Ah[r][1], bl1, ax, 0, 0, 0);
        ax = __builtin_amdgcn_mfma_f32_16x16x32_bf16(Al[r][1], bh1, ax, 0, 0, 0);
#pragma unroll
        for (int reg = 0; reg < 4; ++reg) {
          float dot = am[reg] + ax[reg];
          float dd = fmaf(dot, -2.f, c2v);     // x^2 shift dropped (argmin-invariant)
          const int i = r * 4 + reg;
          float old1 = d1[i];
          bool lt = dd < old1;
          d2[i] = fminf(d2[i], fmaxf(old1, dd));
          d1[i] = lt ? dd : old1;
          k1[i] = lt ? kc : k1[i];
        }
      }
    }

    if (has_next) {
      short8 hh, ll;
#pragma unroll
      for (int e = 0; e < 8; ++e) {
        unsigned short hb = f2bf(pv[e]);
        float lo = pv[e] - bf2f(hb);
        hh[e] = (short)hb; ll[e] = (short)f2bf(lo);
      }
      *(short8*)&Bh[1 - buf][0][sn][spb * 8] = hh;
      *(short8*)&Bh[1 - buf][1][sn][spb * 8] = ll;
    }
    __syncthreads();
  }

  // ---- cross-lane argmin reduce (over the 16 code-columns), k tie-break ----
#pragma unroll
  for (int i = 0; i < 8; ++i) {
    float D1 = d1[i], D2 = d2[i];
    int K1 = k1[i];
#pragma unroll
    for (int off = 1; off < 16; off <<= 1) {
      float o1 = __shfl_xor(D1, off, 64);
      int   ok = __shfl_xor(K1, off, 64);
      float o2 = __shfl_xor(D2, off, 64);
      bool better = (o1 < D1) || (o1 == D1 && ok < K1);
      D2 = fminf(fminf(D2, o2), fmaxf(D1, o1));
      D1 = better ? o1 : D1;
      K1 = better ? ok : K1;
    }
    if (c == 0) {
      int lrow = wave * 32 + (i >> 2) * 16 + q * 4 + (i & 3);
      s_k[lrow] = K1;
      if (D2 - D1 < EPSM) {
        int idx = atomicAdd(&s_nflag, 1);
        s_frows[idx] = lrow;
      }
    }
  }
  __syncthreads();

  // ---- exact fp32 fixup for near-tie rows (replicates round-1 arithmetic) ----
  const int nf = s_nflag;
  for (int f = 0; f < nf; ++f) {
    const int lrow = s_frows[f];
    const float* xr = inp + (size_t)(blockIdx.x * 128 + lrow) * 64;
    float xs[64];
    float x2 = 0.f;
#pragma unroll
    for (int i = 0; i < 16; ++i) {
      float4 v = *(const float4*)(xr + i * 4);
      xs[4 * i + 0] = v.x; xs[4 * i + 1] = v.y; xs[4 * i + 2] = v.z; xs[4 * i + 3] = v.w;
      x2 = fmaf(v.x, v.x, x2); x2 = fmaf(v.y, v.y, x2);
      x2 = fmaf(v.z, v.z, x2); x2 = fmaf(v.w, v.w, x2);
    }
    float dot[8];
#pragma unroll
    for (int cc = 0; cc < 8; ++cc) dot[cc] = 0.f;
    const float* cp = cb + t * 8;
#pragma unroll 4
    for (int d = 0; d < 64; ++d) {
      float xd = xs[d];
#pragma unroll
      for (int cc = 0; cc < 8; ++cc)
        dot[cc] = fmaf(xd, cp[(size_t)d * KCODES + cc], dot[cc]);
    }
    float bd = INFINITY; int bk = 0;
#pragma unroll
    for (int cc = 0; cc < 8; ++cc) {
      float dd = (x2 - 2.0f * dot[cc]) + c2[t * 8 + cc];  // round-1 formula, bit-exact
      if (dd < bd) { bd = dd; bk = t * 8 + cc; }
    }
    s_rd[t] = bd; s_rk[t] = bk;
    __syncthreads();
    for (int s = 128; s >= 1; s >>= 1) {
      if (t < s) {
        if (s_rd[t + s] < s_rd[t]) { s_rd[t] = s_rd[t + s]; s_rk[t] = s_rk[t + s]; }
      }
      __syncthreads();
    }
    if (t == 0) s_k[lrow] = s_rk[0];
    __syncthreads();
  }

  if (t < 128) atomicAdd(&hist[s_k[t]], 1);

  // ---- epilogue: gather q, STE write, SSE ----
  const int fr = t >> 1;
  const int fd = (t & 1) * 32;
  const int grow = blockIdx.x * 128 + fr;
  const int myk = s_k[fr];
  const float* xrow = inp + (size_t)grow * 64 + fd;
  float* orow = out + (size_t)grow * 64 + fd;
  float serr = 0.f;
#pragma unroll
  for (int i = 0; i < 32; ++i) {
    float xv = xrow[i];
    float qv = cb[(size_t)(fd + i) * KCODES + myk];
    float dq = qv - xv;
    serr = fmaf(dq, dq, serr);
    orow[i] = xv + dq;
  }
#pragma unroll
  for (int off = 32; off > 0; off >>= 1) serr += __shfl_down(serr, off, 64);
  if (lane == 0) s_red[wave] = serr;
  __syncthreads();
  if (t == 0) atomicAdd(sse, s_red[0] + s_red[1] + s_red[2] + s_red[3]);
}

__global__ void vq_final(const int* __restrict__ hist,
                         const float* __restrict__ sse,
                         float* __restrict__ out) {
  __shared__ float s_red[4];
  const int t = threadIdx.x;
  float s = 0.f;
  for (int k = t; k < KCODES; k += 256) {
    float p = (float)hist[k] * (1.0f / NROWS);
    s += p * logf(p + 1e-10f);
  }
#pragma unroll
  for (int off = 32; off > 0; off >>= 1) s += __shfl_down(s, off, 64);
  if ((t & 63) == 0) s_red[t >> 6] = s;
  __syncthreads();
  if (t == 0) {
    float tot = s_red[0] + s_red[1] + s_red[2] + s_red[3];
    out[NELEM] = expf(-tot);                 // perplexity
    float cl = *sse * (1.0f / NELEM);
    out[NELEM + 1] = cl;                     // codebook_loss
    out[NELEM + 2] = 0.25f * cl;             // commitment_loss
  }
}

extern "C" void kernel_launch(void* const* d_in, const int* in_sizes, int n_in,
                              void* d_out, int out_size, void* d_ws, size_t ws_size,
                              hipStream_t stream) {
  const float* inp = (const float*)d_in[0];
  const float* cb  = (const float*)d_in[1];
  float* out = (float*)d_out;
  char* ws = (char*)d_ws;
  int* hist  = (int*)(ws + WS_HIST);
  float* c2  = (float*)(ws + WS_C2);
  float* sse = (float*)(ws + WS_SSE);

  hipMemsetAsync(d_ws, 0, WS_SSE + 16, stream);
  vq_colnorm<<<KCODES / 256, 256, 0, stream>>>(cb, c2);
  vq_main<<<NROWS / 128, 256, 0, stream>>>(inp, cb, c2, hist, sse, out);
  vq_final<<<1, 256, 0, stream>>>(hist, sse, out);
}

// Round 3
// 187.798 us; speedup vs baseline: 4.1011x; 1.0985x over previous
//
#include <hip/hip_runtime.h>
#include <math.h>

#define KCODES 2048
#define DIM 64
#define NROWS 65536          // 64*32*32
#define NELEM (NROWS * DIM)  // 4194304

// ws layout (bytes):
//   0      .. 8191   : hist[2048] (int)
//   8192   .. 16383  : c2[2048]  (float)   sum of squares per code (fixup uses)
//   16384  .. 24575  : c2s[2048] (float)   (c2+64)*16384  (packed-argmin bias)
//   24576  .. 24579  : sse (float)
//   32768  .. 557055 : P — codebook as bf16 hi/lo of (-2*c), scaled-layout
//                      [64 tiles][8192B]: per tile, hi region [0,4096),
//                      lo region [4096,8192); byte(sn,g,e) = sn*128 + (g^(sn&7))*16 + e*2
#define WS_HIST 0
#define WS_C2   8192
#define WS_C2S  16384
#define WS_SSE  24576
#define WS_P    32768

#define EPS_PK 33        // EPSM in 2^-14 units: 33*6.1e-5 = 2.01e-3

typedef float  floatx4 __attribute__((ext_vector_type(4)));
typedef short  short8  __attribute__((ext_vector_type(8)));

__device__ __forceinline__ unsigned short f2bf(float f) {
  union { float f; unsigned u; } a; a.f = f;
  unsigned r = (a.u + 0x7FFFu + ((a.u >> 16) & 1u)) >> 16;  // RNE, inputs finite
  return (unsigned short)r;
}
__device__ __forceinline__ float bf2f(unsigned short h) {
  union { unsigned u; float f; } a; a.u = ((unsigned)h) << 16;
  return a.f;
}

// c2[k] = sum_d cb[d][k]^2 (exact round-1 order); c2s[k] = (c2[k]+64)*2^14
__global__ void vq_colnorm(const float* __restrict__ cb, float* __restrict__ c2,
                           float* __restrict__ c2s) {
  int k = blockIdx.x * 256 + threadIdx.x;
  float s = 0.f;
#pragma unroll
  for (int d = 0; d < DIM; ++d) {
    float v = cb[d * KCODES + k];
    s = fmaf(v, v, s);
  }
  c2[k] = s;
  c2s[k] = (s + 64.0f) * 16384.0f;
}

// Pre-split -2*codebook into bf16 hi/lo in the exact LDS staging layout.
// thread -> (code, dim-group g of 8): tid = g*2048 + code
__global__ void vq_prep(const float* __restrict__ cb, char* __restrict__ P) {
  int tid = blockIdx.x * 256 + threadIdx.x;
  int code = tid & (KCODES - 1);
  int g = tid >> 11;              // 0..7
  short8 hh, ll;
#pragma unroll
  for (int e = 0; e < 8; ++e) {
    float v = -2.0f * cb[(size_t)(g * 8 + e) * KCODES + code];
    unsigned short hb = f2bf(v);
    float lo = v - bf2f(hb);
    hh[e] = (short)hb;
    ll[e] = (short)f2bf(lo);
  }
  int tile = code >> 5;
  int sn = code & 31;
  int pb = g ^ (sn & 7);
  size_t base = (size_t)tile * 8192 + sn * 128 + pb * 16;
  *(short8*)(P + base) = hh;          // hi region
  *(short8*)(P + base + 4096) = ll;   // lo region
}

__device__ __forceinline__ void stage_tile(const char* P, char* lds,
                                           int tile, int w, int lane) {
  const char* gp = P + (size_t)tile * 8192 + w * 1024 + lane * 16;
  char* lp = lds + w * 1024 + lane * 16;
  __builtin_amdgcn_global_load_lds(
      (const __attribute__((address_space(1))) unsigned*)gp,
      (__attribute__((address_space(3))) unsigned*)lp, 16, 0, 0);
  __builtin_amdgcn_global_load_lds(
      (const __attribute__((address_space(1))) unsigned*)(gp + 4096),
      (__attribute__((address_space(3))) unsigned*)(lp + 4096), 16, 0, 0);
}

// Block = 256 thr = 4 waves; wave owns 32 rows (2 row-tiles); block = 128 rows.
// K-loop: 64 tiles x 32 codes; B staged via global_load_lds DMA (prepacked),
// 6 chained MFMAs -> acc = -2S*dot; dist packed into uint with k in low 11 bits.
__global__ __launch_bounds__(256, 2) void vq_main(
    const float* __restrict__ inp, const float* __restrict__ cb,
    const float* __restrict__ c2, const float* __restrict__ c2s,
    const char* __restrict__ P, int* __restrict__ hist,
    float* __restrict__ sse, float* __restrict__ out)
{
  __shared__ __align__(16) char Bstage[2][8192];
  __shared__ float s_c2s[KCODES];
  __shared__ int   s_k[128];
  __shared__ int   s_nflag;
  __shared__ int   s_frows[128];
  __shared__ float s_rd[256];
  __shared__ int   s_rk[256];
  __shared__ float s_red[4];

  const int t    = threadIdx.x;
  const int lane = t & 63;
  const int wave = __builtin_amdgcn_readfirstlane(t >> 6);
  const int c    = lane & 15;   // MFMA col (code within 16-group)
  const int q    = lane >> 4;   // MFMA quad
  const int c7   = c & 7;
  const int rowbase = blockIdx.x * 128 + wave * 32;

  if (t == 0) s_nflag = 0;

  // c2s -> LDS table
#pragma unroll
  for (int i = 0; i < KCODES / 256; ++i) s_c2s[i * 256 + t] = c2s[i * 256 + t];

  // ---- A fragments: x rows scaled by 2^14, bf16 hi/lo, [rowtile r][kstep s] ----
  short8 Ah[2][2], Al[2][2];
#pragma unroll
  for (int r = 0; r < 2; ++r) {
#pragma unroll
    for (int s = 0; s < 2; ++s) {
      const float* px = inp + (size_t)(rowbase + r * 16 + c) * 64 + s * 32 + q * 8;
      float4 u0 = *(const float4*)px;
      float4 u1 = *(const float4*)(px + 4);
      float u[8] = {u0.x, u0.y, u0.z, u0.w, u1.x, u1.y, u1.z, u1.w};
      short8 hh, ll;
#pragma unroll
      for (int e = 0; e < 8; ++e) {
        float xs = u[e] * 16384.0f;           // exact pow2 scale
        unsigned short hb = f2bf(xs);
        float lo = xs - bf2f(hb);
        hh[e] = (short)hb;
        ll[e] = (short)f2bf(lo);
      }
      Ah[r][s] = hh; Al[r][s] = ll;
    }
  }

  // packed (dist<<11 | k) best / second-best per lane for 8 rows
  unsigned d1[8], d2[8];
#pragma unroll
  for (int i = 0; i < 8; ++i) { d1[i] = 0xFFFFFFFFu; d2[i] = 0xFFFFFFFFu; }

  stage_tile(P, Bstage[0], 0, wave, lane);
  __syncthreads();

  const floatx4 zero = {0.f, 0.f, 0.f, 0.f};

#pragma unroll 2
  for (int j = 0; j < 64; ++j) {
    const int buf = j & 1;
    if (j + 1 < 64) stage_tile(P, Bstage[1 - buf], j + 1, wave, lane);

    float c2v0 = s_c2s[j * 32 + c];
    float c2v1 = s_c2s[j * 32 + 16 + c];

#pragma unroll
    for (int nt = 0; nt < 2; ++nt) {
      const int rowi = nt * 16 + c;
      const char* bp = &Bstage[buf][rowi * 128];
      short8 bh0 = *(const short8*)(bp + ((0 + q) ^ c7) * 16);
      short8 bh1 = *(const short8*)(bp + ((4 + q) ^ c7) * 16);
      short8 bl0 = *(const short8*)(bp + 4096 + ((0 + q) ^ c7) * 16);
      short8 bl1 = *(const short8*)(bp + 4096 + ((4 + q) ^ c7) * 16);
      const float c2v = nt ? c2v1 : c2v0;
      const unsigned kcn = j * 32 + nt * 16 + c;
#pragma unroll
      for (int r = 0; r < 2; ++r) {
        // 6-term chain: acc = -2S*dot (small cross terms first)
        floatx4 acc = __builtin_amdgcn_mfma_f32_16x16x32_bf16(Al[r][1], bh1, zero, 0, 0, 0);
        acc = __builtin_amdgcn_mfma_f32_16x16x32_bf16(Ah[r][1], bl1, acc, 0, 0, 0);
        acc = __builtin_amdgcn_mfma_f32_16x16x32_bf16(Al[r][0], bh0, acc, 0, 0, 0);
        acc = __builtin_amdgcn_mfma_f32_16x16x32_bf16(Ah[r][0], bl0, acc, 0, 0, 0);
        acc = __builtin_amdgcn_mfma_f32_16x16x32_bf16(Ah[r][1], bh1, acc, 0, 0, 0);
        acc = __builtin_amdgcn_mfma_f32_16x16x32_bf16(Ah[r][0], bh0, acc, 0, 0, 0);
#pragma unroll
        for (int reg = 0; reg < 4; ++reg) {
          float dds = acc[reg] + c2v;                  // S*(dist+64) > 0
          unsigned u = (((unsigned)dds) << 11) + kcn;  // cvt + lshl_add
          const int i = r * 4 + reg;
          d2[i] = min(d2[i], max(d1[i], u));
          d1[i] = min(d1[i], u);
        }
      }
    }
    __syncthreads();
  }

  // ---- cross-lane argmin reduce over the 16 code-columns (uint min) ----
#pragma unroll
  for (int i = 0; i < 8; ++i) {
    unsigned D1 = d1[i], D2 = d2[i];
#pragma unroll
    for (int off = 1; off < 16; off <<= 1) {
      unsigned o1 = (unsigned)__shfl_xor((int)D1, off, 64);
      unsigned o2 = (unsigned)__shfl_xor((int)D2, off, 64);
      D2 = min(min(D2, o2), max(D1, o1));
      D1 = min(D1, o1);
    }
    if (c == 0) {
      int lrow = wave * 32 + (i >> 2) * 16 + q * 4 + (i & 3);
      s_k[lrow] = (int)(D1 & 2047u);
      if ((int)((D2 >> 11) - (D1 >> 11)) < EPS_PK) {
        int idx = atomicAdd(&s_nflag, 1);
        s_frows[idx] = lrow;
      }
    }
  }
  __syncthreads();

  // ---- exact fp32 fixup for near-tie rows (round-1 arithmetic, proven) ----
  const int nf = s_nflag;
  for (int f = 0; f < nf; ++f) {
    const int lrow = s_frows[f];
    const float* xr = inp + (size_t)(blockIdx.x * 128 + lrow) * 64;
    float xs[64];
    float x2 = 0.f;
#pragma unroll
    for (int i = 0; i < 16; ++i) {
      float4 v = *(const float4*)(xr + i * 4);
      xs[4 * i + 0] = v.x; xs[4 * i + 1] = v.y; xs[4 * i + 2] = v.z; xs[4 * i + 3] = v.w;
      x2 = fmaf(v.x, v.x, x2); x2 = fmaf(v.y, v.y, x2);
      x2 = fmaf(v.z, v.z, x2); x2 = fmaf(v.w, v.w, x2);
    }
    float dot[8];
#pragma unroll
    for (int cc = 0; cc < 8; ++cc) dot[cc] = 0.f;
    const float* cp = cb + t * 8;
#pragma unroll 4
    for (int d = 0; d < 64; ++d) {
      float xd = xs[d];
#pragma unroll
      for (int cc = 0; cc < 8; ++cc)
        dot[cc] = fmaf(xd, cp[(size_t)d * KCODES + cc], dot[cc]);
    }
    float bd = INFINITY; int bk = 0;
#pragma unroll
    for (int cc = 0; cc < 8; ++cc) {
      float dd = (x2 - 2.0f * dot[cc]) + c2[t * 8 + cc];
      if (dd < bd) { bd = dd; bk = t * 8 + cc; }
    }
    s_rd[t] = bd; s_rk[t] = bk;
    __syncthreads();
    for (int s = 128; s >= 1; s >>= 1) {
      if (t < s) {
        if (s_rd[t + s] < s_rd[t]) { s_rd[t] = s_rd[t + s]; s_rk[t] = s_rk[t + s]; }
      }
      __syncthreads();
    }
    if (t == 0) s_k[lrow] = s_rk[0];
    __syncthreads();
  }

  if (t < 128) atomicAdd(&hist[s_k[t]], 1);

  // ---- epilogue: gather q, STE write, SSE ----
  const int fr = t >> 1;
  const int fd = (t & 1) * 32;
  const int grow = blockIdx.x * 128 + fr;
  const int myk = s_k[fr];
  const float* xrow = inp + (size_t)grow * 64 + fd;
  float* orow = out + (size_t)grow * 64 + fd;
  float serr = 0.f;
#pragma unroll
  for (int i = 0; i < 32; ++i) {
    float xv = xrow[i];
    float qv = cb[(size_t)(fd + i) * KCODES + myk];
    float dq = qv - xv;
    serr = fmaf(dq, dq, serr);
    orow[i] = xv + dq;
  }
#pragma unroll
  for (int off = 32; off > 0; off >>= 1) serr += __shfl_down(serr, off, 64);
  if (lane == 0) s_red[wave] = serr;
  __syncthreads();
  if (t == 0) atomicAdd(sse, s_red[0] + s_red[1] + s_red[2] + s_red[3]);
}

__global__ void vq_final(const int* __restrict__ hist,
                         const float* __restrict__ sse,
                         float* __restrict__ out) {
  __shared__ float s_red[4];
  const int t = threadIdx.x;
  float s = 0.f;
  for (int k = t; k < KCODES; k += 256) {
    float p = (float)hist[k] * (1.0f / NROWS);
    s += p * logf(p + 1e-10f);
  }
#pragma unroll
  for (int off = 32; off > 0; off >>= 1) s += __shfl_down(s, off, 64);
  if ((t & 63) == 0) s_red[t >> 6] = s;
  __syncthreads();
  if (t == 0) {
    float tot = s_red[0] + s_red[1] + s_red[2] + s_red[3];
    out[NELEM] = expf(-tot);                 // perplexity
    float cl = *sse * (1.0f / NELEM);
    out[NELEM + 1] = cl;                     // codebook_loss
    out[NELEM + 2] = 0.25f * cl;             // commitment_loss
  }
}

extern "C" void kernel_launch(void* const* d_in, const int* in_sizes, int n_in,
                              void* d_out, int out_size, void* d_ws, size_t ws_size,
                              hipStream_t stream) {
  const float* inp = (const float*)d_in[0];
  const float* cb  = (const float*)d_in[1];
  float* out = (float*)d_out;
  char* ws = (char*)d_ws;
  int*   hist = (int*)(ws + WS_HIST);
  float* c2   = (float*)(ws + WS_C2);
  float* c2s  = (float*)(ws + WS_C2S);
  float* sse  = (float*)(ws + WS_SSE);
  char*  P    = ws + WS_P;

  hipMemsetAsync(d_ws, 0, WS_SSE + 16, stream);
  vq_colnorm<<<KCODES / 256, 256, 0, stream>>>(cb, c2, c2s);
  vq_prep<<<KCODES * 8 / 256, 256, 0, stream>>>(cb, P);
  vq_main<<<NROWS / 128, 256, 0, stream>>>(inp, cb, c2, c2s, P, hist, sse, out);
  vq_final<<<1, 256, 0, stream>>>(hist, sse, out);
}